// Round 1
// baseline (1028.680 us; speedup 1.0000x reference)
//
#include <hip/hip_runtime.h>

#define NN 512
#define NN2 (NN * NN)        // 262144 = 2^18
#define BB 64

__device__ __forceinline__ float sigf(float x) {
    return 1.0f / (1.0f + expf(-x));
}

// Push phase. occ layout used directly: row i pairs with p[0]/u[0], col j with p[1]/u[1].
// out must be pre-zeroed; all writes are atomic adds.
__global__ void __launch_bounds__(256) push_kernel(
        const float* __restrict__ occ,
        const float* __restrict__ as_,
        const float* __restrict__ ae_,
        float* __restrict__ out) {
    int idx = blockIdx.x * blockDim.x + threadIdx.x;
    int b   = idx >> 18;
    int rem = idx & (NN2 - 1);
    int i   = rem >> 9;       // row (x-coordinate)
    int j   = rem & (NN - 1); // col (y-coordinate)

    float p0x = as_[2 * b],     p0y = as_[2 * b + 1];
    float p1x = ae_[2 * b],     p1y = ae_[2 * b + 1];
    float dx = p1x - p0x, dy = p1y - p0y;
    float L  = sqrtf(dx * dx + dy * dy + 1e-12f);
    float u0 = dx / L, u1 = dy / L;

    float rx = (float)i - p0x;
    float ry = (float)j - p0y;
    float s  = rx * u0 + ry * u1;
    float t  = -rx * u1 + ry * u0;

    float mask = sigf(3.0f - fabsf(t)) * sigf(s) * sigf(L - s);
    float rho  = occ[idx];
    float base = rho * (1.0f - mask);
    atomicAdd(out + idx, base);

    float moved = rho * mask;
    if (moved > 1e-10f) {
        float disp = fmaxf(L - s, 0.0f);
        float xf = (float)i + disp * u0;
        float yf = (float)j + disp * u1;
        float x0 = floorf(xf), y0 = floorf(yf);
        float fx = xf - x0,    fy = yf - y0;
        int   xi = (int)x0,    yi = (int)y0;
        float* gb = out + ((size_t)b << 18);
        #pragma unroll
        for (int dxc = 0; dxc < 2; ++dxc) {
            #pragma unroll
            for (int dyc = 0; dyc < 2; ++dyc) {
                int ti = xi + dxc;   // row in occ layout
                int tj = yi + dyc;   // col
                float w = (dxc ? fx : 1.0f - fx) * (dyc ? fy : 1.0f - fy);
                if (ti >= 0 && ti < NN && tj >= 0 && tj < NN) {
                    atomicAdd(gb + ti * NN + tj, w * moved);
                }
            }
        }
    }
}

// One redistribution iteration as a gather stencil.
// Constant shift u => floor/frac are per-batch constants.
__global__ void __launch_bounds__(256) redist_kernel(
        const float* __restrict__ rin,
        const float* __restrict__ as_,
        const float* __restrict__ ae_,
        float* __restrict__ rout) {
    int idx = blockIdx.x * blockDim.x + threadIdx.x;
    int b   = idx >> 18;
    int rem = idx & (NN2 - 1);
    int I   = rem >> 9;
    int J   = rem & (NN - 1);

    float p0x = as_[2 * b], p0y = as_[2 * b + 1];
    float p1x = ae_[2 * b], p1y = ae_[2 * b + 1];
    float dx = p1x - p0x, dy = p1y - p0y;
    float dn = sqrtf(dx * dx + dy * dy);

    float r = rin[idx];
    if (dn <= 1e-6f) {        // reference: where(d_norm > 1e-6) picks rho_new
        rout[idx] = r;
        return;
    }
    float u0 = dx / dn, u1 = dy / dn;
    float s0 = floorf(u0), s1 = floorf(u1);
    float f0 = u0 - s0,    f1 = u1 - s1;
    int   si = (int)s0,    sj = (int)s1;

    const float* gb = rin + ((size_t)b << 18);
    float acc = r - fmaxf(r - 1.0f, 0.0f);   // r - exc

    #pragma unroll
    for (int di = 0; di < 2; ++di) {
        #pragma unroll
        for (int dj = 0; dj < 2; ++dj) {
            int src_i = I - si - di;
            int src_j = J - sj - dj;
            float w = (di ? f0 : 1.0f - f0) * (dj ? f1 : 1.0f - f1);
            if (src_i >= 0 && src_i < NN && src_j >= 0 && src_j < NN) {
                float rs = gb[src_i * NN + src_j];
                acc += w * fmaxf(rs - 1.0f, 0.0f);
            }
        }
    }
    rout[idx] = acc;
}

extern "C" void kernel_launch(void* const* d_in, const int* in_sizes, int n_in,
                              void* d_out, int out_size, void* d_ws, size_t ws_size,
                              hipStream_t stream) {
    const float* occ = (const float*)d_in[0];
    const float* as_ = (const float*)d_in[1];
    const float* ae_ = (const float*)d_in[2];
    float* out = (float*)d_out;
    float* ws  = (float*)d_ws;

    const size_t total = (size_t)BB * NN2;   // 16,777,216
    const int threads = 256;
    const int blocks  = (int)(total / threads);

    hipMemsetAsync(d_out, 0, total * sizeof(float), stream);
    push_kernel<<<blocks, threads, 0, stream>>>(occ, as_, ae_, out);

    float* bufs[2] = { out, ws };
    for (int it = 0; it < 10; ++it) {
        redist_kernel<<<blocks, threads, 0, stream>>>(
            bufs[it & 1], as_, ae_, bufs[(it + 1) & 1]);
    }
    // 10 iterations (even) -> final result lands back in d_out.
}